// Round 2
// baseline (1099.385 us; speedup 1.0000x reference)
//
#include <hip/hip_runtime.h>
#include <math.h>

#define N_NODES 50000
#define E_EDGES 1600000
#define TAU     0.5f
#define BN_EPS  1e-5f

// ---------------------------------------------------------------------------
// 1) per-node inverse norm: rn[i] = 1 / (||x_i|| + 1e-12)
__global__ __launch_bounds__(256) void row_inv_norm(
    const float* __restrict__ x, float* __restrict__ rn, int n) {
  int wid  = (int)((blockIdx.x * blockDim.x + threadIdx.x) >> 6);
  int lane = threadIdx.x & 63;
  if (wid >= n) return;
  const float2* row = (const float2*)(x + (size_t)wid * 128);
  float2 v = row[lane];
  float s = v.x * v.x + v.y * v.y;
  #pragma unroll
  for (int off = 32; off; off >>= 1) s += __shfl_xor(s, off);
  if (lane == 0) rn[wid] = 1.0f / (sqrtf(s) + 1e-12f);
}

// ---------------------------------------------------------------------------
// 2) in-degree count (edge_index arrives as int32 from the harness!)
__global__ __launch_bounds__(256) void count_deg(
    const int* __restrict__ dst, int* __restrict__ deg, int e) {
  int i = blockIdx.x * blockDim.x + threadIdx.x;
  if (i < e) atomicAdd(&deg[dst[i]], 1);
}

// ---------------------------------------------------------------------------
// 3) exclusive scan of deg -> rowptr, and cursor := rowptr. Single block.
__global__ void scan_excl(const int* __restrict__ deg, int* __restrict__ rowptr,
                          int* __restrict__ cursor, int n) {
  __shared__ int buf[1024];
  __shared__ int carry;
  if (threadIdx.x == 0) carry = 0;
  __syncthreads();
  for (int base = 0; base < n; base += 1024) {
    int i = base + (int)threadIdx.x;
    int v = (i < n) ? deg[i] : 0;
    buf[threadIdx.x] = v;
    __syncthreads();
    for (int off = 1; off < 1024; off <<= 1) {
      int t = (threadIdx.x >= (unsigned)off) ? buf[threadIdx.x - off] : 0;
      __syncthreads();
      buf[threadIdx.x] += t;
      __syncthreads();
    }
    int incl = buf[threadIdx.x];
    int c = carry;
    if (i < n) {
      rowptr[i] = c + incl - v;
      cursor[i] = c + incl - v;
    }
    __syncthreads();
    if (threadIdx.x == 1023) carry = c + buf[1023];
    __syncthreads();
  }
  if (threadIdx.x == 0) rowptr[n] = carry;
}

// ---------------------------------------------------------------------------
// 4) fused: edge weight (exp(cos_sim/tau)) + CSR fill.
// 16 lanes per edge (2 x float4 each), shfl_xor reduce within the 16-group.
// Order within a segment is arbitrary -> FP summation jitter only.
__global__ __launch_bounds__(256) void fill_csr_fused(
    const float* __restrict__ x, const float* __restrict__ rn,
    const int* __restrict__ src, const int* __restrict__ dst,
    int* __restrict__ cursor, int* __restrict__ csr_src,
    float* __restrict__ csr_w, int e) {
  int g = (int)((blockIdx.x * blockDim.x + threadIdx.x) >> 4);
  int t = threadIdx.x & 15;
  if (g >= e) return;
  int s = src[g], d = dst[g];
  const float4* xs = (const float4*)(x + (size_t)s * 128);
  const float4* xd = (const float4*)(x + (size_t)d * 128);
  float4 a0 = xs[t],      b0 = xd[t];
  float4 a1 = xs[t + 16], b1 = xd[t + 16];
  float acc = a0.x * b0.x + a0.y * b0.y + a0.z * b0.z + a0.w * b0.w
            + a1.x * b1.x + a1.y * b1.y + a1.z * b1.z + a1.w * b1.w;
  acc += __shfl_xor(acc, 1);
  acc += __shfl_xor(acc, 2);
  acc += __shfl_xor(acc, 4);
  acc += __shfl_xor(acc, 8);
  if (t == 0) {
    float w = __expf(acc * rn[s] * rn[d] * (1.0f / TAU));
    int pos = atomicAdd(&cursor[d], 1);
    csr_src[pos] = s;
    csr_w[pos]   = w;
  }
}

// ---------------------------------------------------------------------------
// 5) dual GEMM: Y = H @ Wn ; Z = H @ Wr + (cn + cr)
// block = 256 threads, tile = 32 rows x DO cols. W staged in 64-col halves.
// H is staged into LDS before any global writes, so Z may alias H
// (row-for-row identical regions per block).
template <int DO>
__global__ __launch_bounds__(256) void gemm_dual(
    const float* __restrict__ H,
    const float* __restrict__ Wn, const float* __restrict__ Wr,
    const float* __restrict__ cn, const float* __restrict__ cr,
    float* __restrict__ Y, float* __restrict__ Z, int n) {
  __shared__ float hs[32][129];     // +1 pad: conflict-free row reads
  __shared__ float ws[128 * 64];
  const int t    = threadIdx.x;
  const int row0 = blockIdx.x * 32;

  // stage H tile (32 x 128), coalesced float4
  for (int i = t; i < 1024; i += 256) {
    int r = i >> 5, c4 = i & 31;
    float4 v4 = make_float4(0.f, 0.f, 0.f, 0.f);
    if (row0 + r < n) v4 = ((const float4*)(H + (size_t)(row0 + r) * 128))[c4];
    hs[r][c4 * 4 + 0] = v4.x;
    hs[r][c4 * 4 + 1] = v4.y;
    hs[r][c4 * 4 + 2] = v4.z;
    hs[r][c4 * 4 + 3] = v4.w;
  }

  const int r_l = t >> 3;
  const int cg  = t & 7;
  const int row = row0 + r_l;

  for (int mat = 0; mat < 2; ++mat) {
    const float* W = mat ? Wr : Wn;
    for (int half = 0; half < DO / 64; ++half) {
      __syncthreads();  // previous compute done (and hs visible on 1st pass)
      // stage W[:, half*64 .. +64)  (128 x 64 f32 = 32 KB)
      for (int i = t; i < 128 * 16; i += 256) {
        int kk = i >> 4, c4 = i & 15;
        ((float4*)ws)[i] = ((const float4*)(W + (size_t)kk * DO + half * 64))[c4];
      }
      __syncthreads();

      float acc[8];
      #pragma unroll
      for (int q = 0; q < 8; ++q) acc[q] = 0.0f;

      #pragma unroll 8
      for (int k = 0; k < 128; ++k) {
        float hval = hs[r_l][k];
        const float4* wp = (const float4*)(ws + k * 64 + cg * 8);
        float4 w0 = wp[0], w1 = wp[1];
        acc[0] = fmaf(hval, w0.x, acc[0]);
        acc[1] = fmaf(hval, w0.y, acc[1]);
        acc[2] = fmaf(hval, w0.z, acc[2]);
        acc[3] = fmaf(hval, w0.w, acc[3]);
        acc[4] = fmaf(hval, w1.x, acc[4]);
        acc[5] = fmaf(hval, w1.y, acc[5]);
        acc[6] = fmaf(hval, w1.z, acc[6]);
        acc[7] = fmaf(hval, w1.w, acc[7]);
      }

      if (row < n) {
        int colbase = half * 64 + cg * 8;
        float* dstp = (mat ? Z : Y) + (size_t)row * DO + colbase;
        if (mat) {
          #pragma unroll
          for (int q = 0; q < 8; ++q) acc[q] += cn[colbase + q] + cr[colbase + q];
        }
        ((float4*)dstp)[0] = make_float4(acc[0], acc[1], acc[2], acc[3]);
        ((float4*)dstp)[1] = make_float4(acc[4], acc[5], acc[6], acc[7]);
      }
    }
  }
}

// ---------------------------------------------------------------------------
// 6) aggregation: out[d] = (sum_e w_e * Y[src_e]) / (sum_e w_e + 1e-16) + Z[d]
//    optional BN(eval)+ReLU. One wave per dst node; channels across lanes.
//    Reads only its OWN Z row before writing out -> out may alias Z.
template <int DO, bool DO_BN>
__global__ __launch_bounds__(256) void agg_kernel(
    const float* __restrict__ Y, const float* __restrict__ Zb,
    const int* __restrict__ rowptr, const int* __restrict__ csr_src,
    const float* __restrict__ csr_w,
    const float* __restrict__ g, const float* __restrict__ bb,
    const float* __restrict__ mm, const float* __restrict__ vv,
    float* __restrict__ out, int n) {
  int wid  = (int)((blockIdx.x * blockDim.x + threadIdx.x) >> 6);
  int lane = threadIdx.x & 63;
  if (wid >= n) return;
  int beg = rowptr[wid], end = rowptr[wid + 1];
  float sumw = 0.0f;

  if constexpr (DO == 128) {
    float ax = 0.0f, ay = 0.0f;
    for (int j = beg; j < end; ++j) {
      int   s = csr_src[j];
      float w = csr_w[j];
      float2 val = ((const float2*)(Y + (size_t)s * 128))[lane];
      ax = fmaf(w, val.x, ax);
      ay = fmaf(w, val.y, ay);
      sumw += w;
    }
    float inv = 1.0f / (sumw + 1e-16f);
    float2 z = ((const float2*)(Zb + (size_t)wid * 128))[lane];
    float o0 = fmaf(ax, inv, z.x);
    float o1 = fmaf(ay, inv, z.y);
    if constexpr (DO_BN) {
      int c0 = lane * 2, c1 = c0 + 1;
      float s0 = g[c0] * rsqrtf(vv[c0] + BN_EPS);
      float s1 = g[c1] * rsqrtf(vv[c1] + BN_EPS);
      o0 = fmaxf(fmaf(o0 - mm[c0], s0, bb[c0]), 0.0f);
      o1 = fmaxf(fmaf(o1 - mm[c1], s1, bb[c1]), 0.0f);
    }
    ((float2*)(out + (size_t)wid * 128))[lane] = make_float2(o0, o1);
  } else {
    float ax = 0.0f;
    for (int j = beg; j < end; ++j) {
      int   s = csr_src[j];
      float w = csr_w[j];
      ax = fmaf(w, Y[(size_t)s * 64 + lane], ax);
      sumw += w;
    }
    float inv = 1.0f / (sumw + 1e-16f);
    out[(size_t)wid * 64 + lane] = fmaf(ax, inv, Zb[(size_t)wid * 64 + lane]);
  }
}

// ---------------------------------------------------------------------------
extern "C" void kernel_launch(void* const* d_in, const int* in_sizes, int n_in,
                              void* d_out, int out_size, void* d_ws, size_t ws_size,
                              hipStream_t stream) {
  const float* x   = (const float*)d_in[0];
  const int*   ei  = (const int*)d_in[1];      // int64 in ref -> int32 on device
  const float* Wn0 = (const float*)d_in[2];
  const float* cn0 = (const float*)d_in[3];
  const float* Wr0 = (const float*)d_in[4];
  const float* cr0 = (const float*)d_in[5];
  const float* Wn1 = (const float*)d_in[6];
  const float* cn1 = (const float*)d_in[7];
  const float* Wr1 = (const float*)d_in[8];
  const float* cr1 = (const float*)d_in[9];
  const float* Wn2 = (const float*)d_in[10];
  const float* cn2 = (const float*)d_in[11];
  const float* Wr2 = (const float*)d_in[12];
  const float* cr2 = (const float*)d_in[13];
  const float* g0  = (const float*)d_in[14];
  const float* b0  = (const float*)d_in[15];
  const float* m0  = (const float*)d_in[16];
  const float* v0  = (const float*)d_in[17];
  const float* g1  = (const float*)d_in[18];
  const float* b1  = (const float*)d_in[19];
  const float* m1  = (const float*)d_in[20];
  const float* v1  = (const float*)d_in[21];

  const int* src = ei;
  const int* dst = ei + E_EDGES;

  char* p = (char*)d_ws;
  auto alloc = [&](size_t bytes) {
    char* r = p;
    p += (bytes + 255) & ~(size_t)255;
    return r;
  };
  float* rn      = (float*)alloc((size_t)N_NODES * 4);
  int*   deg     = (int*)  alloc((size_t)N_NODES * 4);
  int*   rowptr  = (int*)  alloc((size_t)(N_NODES + 1) * 4);
  int*   cursor  = (int*)  alloc((size_t)N_NODES * 4);
  int*   csr_src = (int*)  alloc((size_t)E_EDGES * 4);
  float* csr_w   = (float*)alloc((size_t)E_EDGES * 4);
  float* A       = (float*)alloc((size_t)N_NODES * 128 * 4);  // Z / H ping
  float* B       = (float*)alloc((size_t)N_NODES * 128 * 4);  // Y

  hipMemsetAsync(deg, 0, (size_t)N_NODES * 4, stream);

  row_inv_norm<<<(N_NODES + 3) / 4, 256, 0, stream>>>(x, rn, N_NODES);
  count_deg<<<(E_EDGES + 255) / 256, 256, 0, stream>>>(dst, deg, E_EDGES);
  scan_excl<<<1, 1024, 0, stream>>>(deg, rowptr, cursor, N_NODES);
  fill_csr_fused<<<(E_EDGES + 15) / 16, 256, 0, stream>>>(
      x, rn, src, dst, cursor, csr_src, csr_w, E_EDGES);

  const int gemm_grid = (N_NODES + 31) / 32;
  const int agg_grid  = (N_NODES + 3) / 4;

  // layer 0: H = x (read-only input), Y -> B, Z -> A, out -> A
  gemm_dual<128><<<gemm_grid, 256, 0, stream>>>(x, Wn0, Wr0, cn0, cr0, B, A, N_NODES);
  agg_kernel<128, true><<<agg_grid, 256, 0, stream>>>(B, A, rowptr, csr_src, csr_w,
                                                      g0, b0, m0, v0, A, N_NODES);
  // layer 1: H = A, Y -> B, Z -> A (aliases H; staged first), out -> A
  gemm_dual<128><<<gemm_grid, 256, 0, stream>>>(A, Wn1, Wr1, cn1, cr1, B, A, N_NODES);
  agg_kernel<128, true><<<agg_grid, 256, 0, stream>>>(B, A, rowptr, csr_src, csr_w,
                                                      g1, b1, m1, v1, A, N_NODES);
  // layer 2 (64-wide): H = A; pack Y and Z into the two halves of B (no alias)
  float* Y2 = B;
  float* Z2 = B + (size_t)N_NODES * 64;
  gemm_dual<64><<<gemm_grid, 256, 0, stream>>>(A, Wn2, Wr2, cn2, cr2, Y2, Z2, N_NODES);
  agg_kernel<64, false><<<agg_grid, 256, 0, stream>>>(Y2, Z2, rowptr, csr_src, csr_w,
                                                      nullptr, nullptr, nullptr, nullptr,
                                                      (float*)d_out, N_NODES);
}

// Round 3
// 841.845 us; speedup vs baseline: 1.3059x; 1.3059x over previous
//
#include <hip/hip_runtime.h>
#include <hip/hip_fp16.h>
#include <math.h>

#define N_NODES 50000
#define E_EDGES 1600000
#define TAU     0.5f
#define BN_EPS  1e-5f

// ---------------------------------------------------------------------------
// 1) normalized fp16 features: xn[i] = fp16( x_i / (||x_i|| + 1e-12) )
__global__ __launch_bounds__(256) void xn_norm(
    const float* __restrict__ x, __half* __restrict__ xn, int n) {
  int wid  = (int)((blockIdx.x * blockDim.x + threadIdx.x) >> 6);
  int lane = threadIdx.x & 63;
  if (wid >= n) return;
  float2 v = ((const float2*)(x + (size_t)wid * 128))[lane];
  float s = v.x * v.x + v.y * v.y;
  #pragma unroll
  for (int off = 32; off; off >>= 1) s += __shfl_xor(s, off);
  float inv = 1.0f / (sqrtf(s) + 1e-12f);
  ((__half2*)(xn + (size_t)wid * 128))[lane] =
      __floats2half2_rn(v.x * inv, v.y * inv);
}

// ---------------------------------------------------------------------------
// 2) in-degree count (edge_index arrives as int32 from the harness)
__global__ __launch_bounds__(256) void count_deg(
    const int* __restrict__ dst, int* __restrict__ deg, int e) {
  int i = blockIdx.x * blockDim.x + threadIdx.x;
  if (i < e) atomicAdd(&deg[dst[i]], 1);
}

// ---------------------------------------------------------------------------
// 3) exclusive scan: thread-local serial prefix + one block scan (~10 barriers)
__global__ void scan_excl(const int* __restrict__ deg, int* __restrict__ rowptr,
                          int* __restrict__ cursor, int n) {
  __shared__ int part[1024];
  int t = (int)threadIdx.x;
  int per = (n + 1023) / 1024;
  int b0 = t * per;
  int b1 = min(b0 + per, n);
  int s = 0;
  for (int i = b0; i < b1; ++i) s += deg[i];
  part[t] = s;
  __syncthreads();
  for (int off = 1; off < 1024; off <<= 1) {
    int v = (t >= off) ? part[t - off] : 0;
    __syncthreads();
    part[t] += v;
    __syncthreads();
  }
  int run = part[t] - s;   // exclusive prefix of this chunk
  for (int i = b0; i < b1; ++i) {
    rowptr[i] = run;
    cursor[i] = run;
    run += deg[i];
  }
  if (t == 1023) rowptr[n] = run;
}

// ---------------------------------------------------------------------------
// 4) fused: edge weight exp(cos_sim/tau) + packed CSR fill + denom accumulate.
// 16 lanes per edge, each lane 16B (8 halves) of xs and xd.
__global__ __launch_bounds__(256) void fill_csr_fused(
    const __half* __restrict__ xn,
    const int* __restrict__ src, const int* __restrict__ dst,
    int* __restrict__ cursor, int2* __restrict__ csr,
    float* __restrict__ denom, int e) {
  int g = (int)((blockIdx.x * blockDim.x + threadIdx.x) >> 4);
  int t = threadIdx.x & 15;
  if (g >= e) return;
  int s = src[g], d = dst[g];
  int4 av = ((const int4*)(xn + (size_t)s * 128))[t];
  int4 bv = ((const int4*)(xn + (size_t)d * 128))[t];
  float acc = 0.0f;
  {
    const __half2* ah = (const __half2*)&av;
    const __half2* bh = (const __half2*)&bv;
    #pragma unroll
    for (int q = 0; q < 4; ++q) {
      float2 fa = __half22float2(ah[q]);
      float2 fb = __half22float2(bh[q]);
      acc = fmaf(fa.x, fb.x, acc);
      acc = fmaf(fa.y, fb.y, acc);
    }
  }
  acc += __shfl_xor(acc, 1);
  acc += __shfl_xor(acc, 2);
  acc += __shfl_xor(acc, 4);
  acc += __shfl_xor(acc, 8);
  if (t == 0) {
    float w = __expf(acc * (1.0f / TAU));
    int pos = atomicAdd(&cursor[d], 1);
    csr[pos] = make_int2(s, __float_as_int(w));
    atomicAdd(&denom[d], w);
  }
}

// ---------------------------------------------------------------------------
// 5) dual GEMM: Y = fp16(H @ Wn) ; Z = fp16(H @ Wr + cn + cr)
// block = 256 threads, tile = 32 rows x DO cols. W staged in 64-col halves.
template <int DO>
__global__ __launch_bounds__(256) void gemm_dual(
    const float* __restrict__ H,
    const float* __restrict__ Wn, const float* __restrict__ Wr,
    const float* __restrict__ cn, const float* __restrict__ cr,
    __half* __restrict__ Y, __half* __restrict__ Z, int n) {
  __shared__ float hs[32][129];     // +1 pad: conflict-free row reads
  __shared__ float ws[128 * 64];
  const int t    = threadIdx.x;
  const int row0 = blockIdx.x * 32;

  for (int i = t; i < 1024; i += 256) {
    int r = i >> 5, c4 = i & 31;
    float4 v4 = make_float4(0.f, 0.f, 0.f, 0.f);
    if (row0 + r < n) v4 = ((const float4*)(H + (size_t)(row0 + r) * 128))[c4];
    hs[r][c4 * 4 + 0] = v4.x;
    hs[r][c4 * 4 + 1] = v4.y;
    hs[r][c4 * 4 + 2] = v4.z;
    hs[r][c4 * 4 + 3] = v4.w;
  }

  const int r_l = t >> 3;
  const int cg  = t & 7;
  const int row = row0 + r_l;

  for (int mat = 0; mat < 2; ++mat) {
    const float* W = mat ? Wr : Wn;
    for (int half = 0; half < DO / 64; ++half) {
      __syncthreads();
      for (int i = t; i < 128 * 16; i += 256) {
        int kk = i >> 4, c4 = i & 15;
        ((float4*)ws)[i] = ((const float4*)(W + (size_t)kk * DO + half * 64))[c4];
      }
      __syncthreads();

      float acc[8];
      #pragma unroll
      for (int q = 0; q < 8; ++q) acc[q] = 0.0f;

      #pragma unroll 8
      for (int k = 0; k < 128; ++k) {
        float hval = hs[r_l][k];
        const float4* wp = (const float4*)(ws + k * 64 + cg * 8);
        float4 w0 = wp[0], w1 = wp[1];
        acc[0] = fmaf(hval, w0.x, acc[0]);
        acc[1] = fmaf(hval, w0.y, acc[1]);
        acc[2] = fmaf(hval, w0.z, acc[2]);
        acc[3] = fmaf(hval, w0.w, acc[3]);
        acc[4] = fmaf(hval, w1.x, acc[4]);
        acc[5] = fmaf(hval, w1.y, acc[5]);
        acc[6] = fmaf(hval, w1.z, acc[6]);
        acc[7] = fmaf(hval, w1.w, acc[7]);
      }

      if (row < n) {
        int colbase = half * 64 + cg * 8;
        if (mat) {
          #pragma unroll
          for (int q = 0; q < 8; ++q) acc[q] += cn[colbase + q] + cr[colbase + q];
        }
        __half2 h0 = __floats2half2_rn(acc[0], acc[1]);
        __half2 h1 = __floats2half2_rn(acc[2], acc[3]);
        __half2 h2 = __floats2half2_rn(acc[4], acc[5]);
        __half2 h3 = __floats2half2_rn(acc[6], acc[7]);
        int4 pk;
        pk.x = *(int*)&h0; pk.y = *(int*)&h1;
        pk.z = *(int*)&h2; pk.w = *(int*)&h3;
        *((int4*)((mat ? Z : Y) + (size_t)row * DO + colbase)) = pk;
      }
    }
  }
}

// ---------------------------------------------------------------------------
// 6) aggregation: out[d] = (sum_e w_e * Y[src_e]) * inv_denom[d] + Z[d]
//    optional BN(eval)+ReLU. One wave per dst node; channels across lanes.
//    Edge metadata: chunk of 64 packed entries loaded lane-parallel, then
//    broadcast via __shfl (removes per-edge uniform-load latency).
template <int DO, bool DO_BN>
__global__ __launch_bounds__(256) void agg_kernel(
    const __half* __restrict__ Y, const __half* __restrict__ Zb,
    const int* __restrict__ rowptr, const int2* __restrict__ csr,
    const float* __restrict__ denom,
    const float* __restrict__ g, const float* __restrict__ bb,
    const float* __restrict__ mm, const float* __restrict__ vv,
    float* __restrict__ out, int n) {
  int wid  = (int)((blockIdx.x * blockDim.x + threadIdx.x) >> 6);
  int lane = threadIdx.x & 63;
  if (wid >= n) return;
  int beg = rowptr[wid], end = rowptr[wid + 1];
  float inv = 1.0f / (denom[wid] + 1e-16f);

  if constexpr (DO == 128) {
    float ax = 0.0f, ay = 0.0f;
    for (int base = beg; base < end; base += 64) {
      int m = min(64, end - base);
      int2 e = make_int2(0, 0);
      if (lane < m) e = csr[base + lane];
      for (int q = 0; q < m; ++q) {
        int   s = __shfl(e.x, q);
        float w = __int_as_float(__shfl(e.y, q));
        float2 f = __half22float2(((const __half2*)(Y + (size_t)s * 128))[lane]);
        ax = fmaf(w, f.x, ax);
        ay = fmaf(w, f.y, ay);
      }
    }
    float2 z = __half22float2(((const __half2*)(Zb + (size_t)wid * 128))[lane]);
    float o0 = fmaf(ax, inv, z.x);
    float o1 = fmaf(ay, inv, z.y);
    if constexpr (DO_BN) {
      int c0 = lane * 2, c1 = c0 + 1;
      float s0 = g[c0] * rsqrtf(vv[c0] + BN_EPS);
      float s1 = g[c1] * rsqrtf(vv[c1] + BN_EPS);
      o0 = fmaxf(fmaf(o0 - mm[c0], s0, bb[c0]), 0.0f);
      o1 = fmaxf(fmaf(o1 - mm[c1], s1, bb[c1]), 0.0f);
    }
    ((float2*)(out + (size_t)wid * 128))[lane] = make_float2(o0, o1);
  } else {
    float ax = 0.0f;
    for (int base = beg; base < end; base += 64) {
      int m = min(64, end - base);
      int2 e = make_int2(0, 0);
      if (lane < m) e = csr[base + lane];
      for (int q = 0; q < m; ++q) {
        int   s = __shfl(e.x, q);
        float w = __int_as_float(__shfl(e.y, q));
        ax = fmaf(w, __half2float(Y[(size_t)s * 64 + lane]), ax);
      }
    }
    float z = __half2float(Zb[(size_t)wid * 64 + lane]);
    out[(size_t)wid * 64 + lane] = fmaf(ax, inv, z);
  }
}

// ---------------------------------------------------------------------------
extern "C" void kernel_launch(void* const* d_in, const int* in_sizes, int n_in,
                              void* d_out, int out_size, void* d_ws, size_t ws_size,
                              hipStream_t stream) {
  const float* x   = (const float*)d_in[0];
  const int*   ei  = (const int*)d_in[1];      // int64 in ref -> int32 on device
  const float* Wn0 = (const float*)d_in[2];
  const float* cn0 = (const float*)d_in[3];
  const float* Wr0 = (const float*)d_in[4];
  const float* cr0 = (const float*)d_in[5];
  const float* Wn1 = (const float*)d_in[6];
  const float* cn1 = (const float*)d_in[7];
  const float* Wr1 = (const float*)d_in[8];
  const float* cr1 = (const float*)d_in[9];
  const float* Wn2 = (const float*)d_in[10];
  const float* cn2 = (const float*)d_in[11];
  const float* Wr2 = (const float*)d_in[12];
  const float* cr2 = (const float*)d_in[13];
  const float* g0  = (const float*)d_in[14];
  const float* b0  = (const float*)d_in[15];
  const float* m0  = (const float*)d_in[16];
  const float* v0  = (const float*)d_in[17];
  const float* g1  = (const float*)d_in[18];
  const float* b1  = (const float*)d_in[19];
  const float* m1  = (const float*)d_in[20];
  const float* v1  = (const float*)d_in[21];

  const int* src = ei;
  const int* dst = ei + E_EDGES;

  char* p = (char*)d_ws;
  auto alloc = [&](size_t bytes) {
    char* r = p;
    p += (bytes + 255) & ~(size_t)255;
    return r;
  };
  __half* P0     = (__half*)alloc((size_t)N_NODES * 128 * 2);  // xn, then Yh
  __half* P1     = (__half*)alloc((size_t)N_NODES * 128 * 2);  // Zh
  int*    deg    = (int*)  alloc((size_t)N_NODES * 4);
  float*  denom  = (float*)alloc((size_t)N_NODES * 4);
  int*    rowptr = (int*)  alloc((size_t)(N_NODES + 1) * 4);
  int*    cursor = (int*)  alloc((size_t)N_NODES * 4);
  int2*   csr    = (int2*) alloc((size_t)E_EDGES * 8);
  float*  A      = (float*)alloc((size_t)N_NODES * 128 * 4);   // H (f32)

  hipMemsetAsync(deg, 0, (size_t)N_NODES * 4, stream);
  hipMemsetAsync(denom, 0, (size_t)N_NODES * 4, stream);

  xn_norm<<<(N_NODES + 3) / 4, 256, 0, stream>>>(x, P0, N_NODES);
  count_deg<<<(E_EDGES + 255) / 256, 256, 0, stream>>>(dst, deg, E_EDGES);
  scan_excl<<<1, 1024, 0, stream>>>(deg, rowptr, cursor, N_NODES);
  fill_csr_fused<<<(E_EDGES + 15) / 16, 256, 0, stream>>>(
      P0, src, dst, cursor, csr, denom, E_EDGES);

  const int gemm_grid = (N_NODES + 31) / 32;
  const int agg_grid  = (N_NODES + 3) / 4;

  // layer 0: H = x, Y -> P0 (overwrites xn after fill), Z -> P1, out -> A
  gemm_dual<128><<<gemm_grid, 256, 0, stream>>>(x, Wn0, Wr0, cn0, cr0, P0, P1, N_NODES);
  agg_kernel<128, true><<<agg_grid, 256, 0, stream>>>(P0, P1, rowptr, csr, denom,
                                                      g0, b0, m0, v0, A, N_NODES);
  // layer 1: H = A, Y -> P0, Z -> P1, out -> A
  gemm_dual<128><<<gemm_grid, 256, 0, stream>>>(A, Wn1, Wr1, cn1, cr1, P0, P1, N_NODES);
  agg_kernel<128, true><<<agg_grid, 256, 0, stream>>>(P0, P1, rowptr, csr, denom,
                                                      g1, b1, m1, v1, A, N_NODES);
  // layer 2 (64-wide): H = A, Y -> P0, Z -> P1, out -> d_out (f32)
  gemm_dual<64><<<gemm_grid, 256, 0, stream>>>(A, Wn2, Wr2, cn2, cr2, P0, P1, N_NODES);
  agg_kernel<64, false><<<agg_grid, 256, 0, stream>>>(P0, P1, rowptr, csr, denom,
                                                      nullptr, nullptr, nullptr, nullptr,
                                                      (float*)d_out, N_NODES);
}

// Round 4
// 728.212 us; speedup vs baseline: 1.5097x; 1.1560x over previous
//
#include <hip/hip_runtime.h>
#include <hip/hip_fp16.h>
#include <math.h>

#define N_NODES 50000
#define E_EDGES 1600000
#define TAU     0.5f
#define BN_EPS  1e-5f

// ---------------------------------------------------------------------------
// 1) normalized fp16 features: xn[i] = fp16( x_i / (||x_i|| + 1e-12) )
__global__ __launch_bounds__(256) void xn_norm(
    const float* __restrict__ x, __half* __restrict__ xn, int n) {
  int wid  = (int)((blockIdx.x * blockDim.x + threadIdx.x) >> 6);
  int lane = threadIdx.x & 63;
  if (wid >= n) return;
  float2 v = ((const float2*)(x + (size_t)wid * 128))[lane];
  float s = v.x * v.x + v.y * v.y;
  #pragma unroll
  for (int off = 32; off; off >>= 1) s += __shfl_xor(s, off);
  float inv = 1.0f / (sqrtf(s) + 1e-12f);
  ((__half2*)(xn + (size_t)wid * 128))[lane] =
      __floats2half2_rn(v.x * inv, v.y * inv);
}

// ---------------------------------------------------------------------------
// 2) in-degree count (edge_index arrives as int32 from the harness)
__global__ __launch_bounds__(256) void count_deg(
    const int* __restrict__ dst, int* __restrict__ deg, int e) {
  int i = blockIdx.x * blockDim.x + threadIdx.x;
  if (i < e) atomicAdd(&deg[dst[i]], 1);
}

// ---------------------------------------------------------------------------
// 3) exclusive scan: thread-local serial prefix + one block scan
__global__ void scan_excl(const int* __restrict__ deg, int* __restrict__ rowptr,
                          int* __restrict__ cursor, int n) {
  __shared__ int part[1024];
  int t = (int)threadIdx.x;
  int per = (n + 1023) / 1024;
  int b0 = t * per;
  int b1 = min(b0 + per, n);
  int s = 0;
  for (int i = b0; i < b1; ++i) s += deg[i];
  part[t] = s;
  __syncthreads();
  for (int off = 1; off < 1024; off <<= 1) {
    int v = (t >= off) ? part[t - off] : 0;
    __syncthreads();
    part[t] += v;
    __syncthreads();
  }
  int run = part[t] - s;   // exclusive prefix of this chunk
  for (int i = b0; i < b1; ++i) {
    rowptr[i] = run;
    cursor[i] = run;
    run += deg[i];
  }
  if (t == 1023) rowptr[n] = run;
}

// ---------------------------------------------------------------------------
// 4) fused: edge weight exp(cos_sim/tau) + packed 4B CSR fill + denom.
// 8 lanes per edge (2 x int4 = 32B per side per lane) -> 8 edges/wave in flight.
__global__ __launch_bounds__(256) void fill_csr_fused(
    const __half* __restrict__ xn,
    const int* __restrict__ src, const int* __restrict__ dst,
    int* __restrict__ cursor, unsigned* __restrict__ csr,
    float* __restrict__ denom, int e) {
  int g = (int)((blockIdx.x * blockDim.x + threadIdx.x) >> 3);
  int t = threadIdx.x & 7;
  if (g >= e) return;
  int s = src[g], d = dst[g];
  const int4* xs = (const int4*)(xn + (size_t)s * 128);
  const int4* xd = (const int4*)(xn + (size_t)d * 128);
  int4 a0 = xs[t], a1 = xs[t + 8];
  int4 b0 = xd[t], b1 = xd[t + 8];
  float acc = 0.0f;
  {
    const __half2* ah0 = (const __half2*)&a0;
    const __half2* bh0 = (const __half2*)&b0;
    const __half2* ah1 = (const __half2*)&a1;
    const __half2* bh1 = (const __half2*)&b1;
    #pragma unroll
    for (int q = 0; q < 4; ++q) {
      float2 fa = __half22float2(ah0[q]);
      float2 fb = __half22float2(bh0[q]);
      acc = fmaf(fa.x, fb.x, acc);
      acc = fmaf(fa.y, fb.y, acc);
      fa = __half22float2(ah1[q]);
      fb = __half22float2(bh1[q]);
      acc = fmaf(fa.x, fb.x, acc);
      acc = fmaf(fa.y, fb.y, acc);
    }
  }
  acc += __shfl_xor(acc, 1);
  acc += __shfl_xor(acc, 2);
  acc += __shfl_xor(acc, 4);
  if (t == 0) {
    float w = __expf(acc * (1.0f / TAU));
    int pos = atomicAdd(&cursor[d], 1);
    unsigned w16 = (unsigned)__half_as_ushort(__float2half_rn(w));
    csr[pos] = (unsigned)s | (w16 << 16);
    atomicAdd(&denom[d], w);
  }
}

// ---------------------------------------------------------------------------
// 5) dual GEMM: Y = fp16(H @ Wn) ; Z = fp16(H @ Wr + cn + cr)
template <int DO>
__global__ __launch_bounds__(256) void gemm_dual(
    const float* __restrict__ H,
    const float* __restrict__ Wn, const float* __restrict__ Wr,
    const float* __restrict__ cn, const float* __restrict__ cr,
    __half* __restrict__ Y, __half* __restrict__ Z, int n) {
  __shared__ float hs[32][129];     // +1 pad: conflict-free row reads
  __shared__ float ws[128 * 64];
  const int t    = threadIdx.x;
  const int row0 = blockIdx.x * 32;

  for (int i = t; i < 1024; i += 256) {
    int r = i >> 5, c4 = i & 31;
    float4 v4 = make_float4(0.f, 0.f, 0.f, 0.f);
    if (row0 + r < n) v4 = ((const float4*)(H + (size_t)(row0 + r) * 128))[c4];
    hs[r][c4 * 4 + 0] = v4.x;
    hs[r][c4 * 4 + 1] = v4.y;
    hs[r][c4 * 4 + 2] = v4.z;
    hs[r][c4 * 4 + 3] = v4.w;
  }

  const int r_l = t >> 3;
  const int cg  = t & 7;
  const int row = row0 + r_l;

  for (int mat = 0; mat < 2; ++mat) {
    const float* W = mat ? Wr : Wn;
    for (int half = 0; half < DO / 64; ++half) {
      __syncthreads();
      for (int i = t; i < 128 * 16; i += 256) {
        int kk = i >> 4, c4 = i & 15;
        ((float4*)ws)[i] = ((const float4*)(W + (size_t)kk * DO + half * 64))[c4];
      }
      __syncthreads();

      float acc[8];
      #pragma unroll
      for (int q = 0; q < 8; ++q) acc[q] = 0.0f;

      #pragma unroll 8
      for (int k = 0; k < 128; ++k) {
        float hval = hs[r_l][k];
        const float4* wp = (const float4*)(ws + k * 64 + cg * 8);
        float4 w0 = wp[0], w1 = wp[1];
        acc[0] = fmaf(hval, w0.x, acc[0]);
        acc[1] = fmaf(hval, w0.y, acc[1]);
        acc[2] = fmaf(hval, w0.z, acc[2]);
        acc[3] = fmaf(hval, w0.w, acc[3]);
        acc[4] = fmaf(hval, w1.x, acc[4]);
        acc[5] = fmaf(hval, w1.y, acc[5]);
        acc[6] = fmaf(hval, w1.z, acc[6]);
        acc[7] = fmaf(hval, w1.w, acc[7]);
      }

      if (row < n) {
        int colbase = half * 64 + cg * 8;
        if (mat) {
          #pragma unroll
          for (int q = 0; q < 8; ++q) acc[q] += cn[colbase + q] + cr[colbase + q];
        }
        __half2 h0 = __floats2half2_rn(acc[0], acc[1]);
        __half2 h1 = __floats2half2_rn(acc[2], acc[3]);
        __half2 h2 = __floats2half2_rn(acc[4], acc[5]);
        __half2 h3 = __floats2half2_rn(acc[6], acc[7]);
        int4 pk;
        pk.x = *(int*)&h0; pk.y = *(int*)&h1;
        pk.z = *(int*)&h2; pk.w = *(int*)&h3;
        *((int4*)((mat ? Z : Y) + (size_t)row * DO + colbase)) = pk;
      }
    }
  }
}

// ---------------------------------------------------------------------------
// 6) aggregation: out[d] = (sum_e w_e * Y[src_e]) * inv_denom[d] + Z[d]
//    DO=128: 2 edges in flight (half-wave each, int2 = 4 ch/lane)
//    DO=64 : 4 edges in flight (16-lane groups, int2 = 4 ch/lane)
//    Edge words prefetched 64 at a time, broadcast via __shfl.
template <int DO, bool DO_BN>
__global__ __launch_bounds__(256) void agg_kernel(
    const __half* __restrict__ Y, const __half* __restrict__ Zb,
    const int* __restrict__ rowptr, const unsigned* __restrict__ csr,
    const float* __restrict__ denom,
    const float* __restrict__ g, const float* __restrict__ bb,
    const float* __restrict__ mm, const float* __restrict__ vv,
    float* __restrict__ out, int n) {
  int wid  = (int)((blockIdx.x * blockDim.x + threadIdx.x) >> 6);
  int lane = threadIdx.x & 63;
  if (wid >= n) return;
  int beg = rowptr[wid], end = rowptr[wid + 1];
  float inv = 1.0f / (denom[wid] + 1e-16f);

  constexpr int EPAR = (DO == 128) ? 2 : 4;      // edges in flight
  const int grp = lane / (64 / EPAR);            // which edge of the group
  const int sub = lane & (64 / EPAR - 1);        // channel-quad index

  float a0 = 0.f, a1 = 0.f, a2 = 0.f, a3 = 0.f;
  for (int base = beg; base < end; base += 64) {
    int m = min(64, end - base);
    unsigned pk = (lane < m) ? csr[base + lane] : 0u;   // w=0 for inactive
    int iters = (m + EPAR - 1) / EPAR;
    #pragma unroll 4
    for (int q = 0; q < iters; ++q) {
      unsigned u = __shfl(pk, q * EPAR + grp);
      int   s = (int)(u & 0xFFFFu);
      float w = __half2float(__ushort_as_half((unsigned short)(u >> 16)));
      int2 raw = ((const int2*)(Y + (size_t)s * DO))[sub];
      float2 f0 = __half22float2(*(const __half2*)&raw.x);
      float2 f1 = __half22float2(*(const __half2*)&raw.y);
      a0 = fmaf(w, f0.x, a0);
      a1 = fmaf(w, f0.y, a1);
      a2 = fmaf(w, f1.x, a2);
      a3 = fmaf(w, f1.y, a3);
    }
  }
  // combine across edge groups
  #pragma unroll
  for (int off = 32; off >= 64 / EPAR; off >>= 1) {
    a0 += __shfl_xor(a0, off);
    a1 += __shfl_xor(a1, off);
    a2 += __shfl_xor(a2, off);
    a3 += __shfl_xor(a3, off);
  }

  if (lane < 64 / EPAR) {
    int c = sub * 4;
    int2 zraw = ((const int2*)(Zb + (size_t)wid * DO))[sub];
    float2 z0 = __half22float2(*(const __half2*)&zraw.x);
    float2 z1 = __half22float2(*(const __half2*)&zraw.y);
    float o0 = fmaf(a0, inv, z0.x);
    float o1 = fmaf(a1, inv, z0.y);
    float o2 = fmaf(a2, inv, z1.x);
    float o3 = fmaf(a3, inv, z1.y);
    if constexpr (DO_BN) {
      float s0 = g[c + 0] * rsqrtf(vv[c + 0] + BN_EPS);
      float s1 = g[c + 1] * rsqrtf(vv[c + 1] + BN_EPS);
      float s2 = g[c + 2] * rsqrtf(vv[c + 2] + BN_EPS);
      float s3 = g[c + 3] * rsqrtf(vv[c + 3] + BN_EPS);
      o0 = fmaxf(fmaf(o0 - mm[c + 0], s0, bb[c + 0]), 0.0f);
      o1 = fmaxf(fmaf(o1 - mm[c + 1], s1, bb[c + 1]), 0.0f);
      o2 = fmaxf(fmaf(o2 - mm[c + 2], s2, bb[c + 2]), 0.0f);
      o3 = fmaxf(fmaf(o3 - mm[c + 3], s3, bb[c + 3]), 0.0f);
    }
    ((float4*)(out + (size_t)wid * DO))[sub] = make_float4(o0, o1, o2, o3);
  }
}

// ---------------------------------------------------------------------------
extern "C" void kernel_launch(void* const* d_in, const int* in_sizes, int n_in,
                              void* d_out, int out_size, void* d_ws, size_t ws_size,
                              hipStream_t stream) {
  const float* x   = (const float*)d_in[0];
  const int*   ei  = (const int*)d_in[1];      // int64 in ref -> int32 on device
  const float* Wn0 = (const float*)d_in[2];
  const float* cn0 = (const float*)d_in[3];
  const float* Wr0 = (const float*)d_in[4];
  const float* cr0 = (const float*)d_in[5];
  const float* Wn1 = (const float*)d_in[6];
  const float* cn1 = (const float*)d_in[7];
  const float* Wr1 = (const float*)d_in[8];
  const float* cr1 = (const float*)d_in[9];
  const float* Wn2 = (const float*)d_in[10];
  const float* cn2 = (const float*)d_in[11];
  const float* Wr2 = (const float*)d_in[12];
  const float* cr2 = (const float*)d_in[13];
  const float* g0  = (const float*)d_in[14];
  const float* b0  = (const float*)d_in[15];
  const float* m0  = (const float*)d_in[16];
  const float* v0  = (const float*)d_in[17];
  const float* g1  = (const float*)d_in[18];
  const float* b1  = (const float*)d_in[19];
  const float* m1  = (const float*)d_in[20];
  const float* v1  = (const float*)d_in[21];

  const int* src = ei;
  const int* dst = ei + E_EDGES;

  char* p = (char*)d_ws;
  auto alloc = [&](size_t bytes) {
    char* r = p;
    p += (bytes + 255) & ~(size_t)255;
    return r;
  };
  __half*   P0     = (__half*)  alloc((size_t)N_NODES * 128 * 2);  // xn, then Yh
  __half*   P1     = (__half*)  alloc((size_t)N_NODES * 128 * 2);  // Zh
  int*      degden = (int*)     alloc((size_t)N_NODES * 8);        // deg | denom
  int*      rowptr = (int*)     alloc((size_t)(N_NODES + 1) * 4);
  int*      cursor = (int*)     alloc((size_t)N_NODES * 4);
  unsigned* csr    = (unsigned*)alloc((size_t)E_EDGES * 4);
  float*    A      = (float*)   alloc((size_t)N_NODES * 128 * 4);  // H (f32)

  int*   deg   = degden;
  float* denom = (float*)(degden + N_NODES);

  hipMemsetAsync(degden, 0, (size_t)N_NODES * 8, stream);

  xn_norm<<<(N_NODES + 3) / 4, 256, 0, stream>>>(x, P0, N_NODES);
  count_deg<<<(E_EDGES + 255) / 256, 256, 0, stream>>>(dst, deg, E_EDGES);
  scan_excl<<<1, 1024, 0, stream>>>(deg, rowptr, cursor, N_NODES);
  fill_csr_fused<<<(E_EDGES + 31) / 32, 256, 0, stream>>>(
      P0, src, dst, cursor, csr, denom, E_EDGES);

  const int gemm_grid = (N_NODES + 31) / 32;
  const int agg_grid  = (N_NODES + 3) / 4;

  // layer 0: H = x, Y -> P0 (overwrites xn after fill), Z -> P1, out -> A
  gemm_dual<128><<<gemm_grid, 256, 0, stream>>>(x, Wn0, Wr0, cn0, cr0, P0, P1, N_NODES);
  agg_kernel<128, true><<<agg_grid, 256, 0, stream>>>(P0, P1, rowptr, csr, denom,
                                                      g0, b0, m0, v0, A, N_NODES);
  // layer 1: H = A, Y -> P0, Z -> P1, out -> A
  gemm_dual<128><<<gemm_grid, 256, 0, stream>>>(A, Wn1, Wr1, cn1, cr1, P0, P1, N_NODES);
  agg_kernel<128, true><<<agg_grid, 256, 0, stream>>>(P0, P1, rowptr, csr, denom,
                                                      g1, b1, m1, v1, A, N_NODES);
  // layer 2 (64-wide): H = A, Y -> P0, Z -> P1, out -> d_out (f32)
  gemm_dual<64><<<gemm_grid, 256, 0, stream>>>(A, Wn2, Wr2, cn2, cr2, P0, P1, N_NODES);
  agg_kernel<64, false><<<agg_grid, 256, 0, stream>>>(P0, P1, rowptr, csr, denom,
                                                      nullptr, nullptr, nullptr, nullptr,
                                                      (float*)d_out, N_NODES);
}